// Round 12
// baseline (424.599 us; speedup 1.0000x reference)
//
#include <hip/hip_runtime.h>
#include <hip/hip_fp16.h>

// Bidirectional char-LSTM + masked max-pool via MFMA, operand-swapped,
// CH=2 with 8x-duplicated B-columns + SIMT role-split activation.
// 256 blocks = 2 dirs x 128 chain-pairs -> ALL 256 CUs active (R11: 128).
// Each (chain,dim) task is owned by a LANE PAIR (l15, l15^8): B-cols are
// duplicated so both lanes hold identical gate values. Nonlinearities are
// split SIMT-uniformly: role A (flag=0) computes sig(f),sig(i); role B
// computes sig(2g),sig(o) with the SAME instructions on cndmask-selected
// inputs (tanh(x) = 2*sig(2x)-1); exchange via 3 ds_swizzle(xor 8); both
// compute tanh(c). Per-lane nonlins 10 -> 6 trans, depth 4 -> 2.
// Per step: D'[512 gates][16 cols(2 chains x8)] = W[512][192] x H[192][16]
// via mfma_f32_16x16x32_f16; W static in VGPRs (24 f16x8/wave); H in LDS,
// fragment-ordered (lane l reads bytes [l*16,l*16+16) -> conflict-free).
// h-writeback: 8 copies split 4+4 across the pair. One barrier per step.

#define TT 512
#define CH 2

typedef _Float16 f16;
typedef _Float16 f16x8 __attribute__((ext_vector_type(8)));
typedef float f32x4 __attribute__((ext_vector_type(4)));
typedef unsigned int u32;
typedef unsigned short u16;

static __device__ __forceinline__ u32 packh2(float lo, float hi) {
    union { struct { f16 x, y; } h; u32 u; } cv;
    cv.h.x = (f16)lo; cv.h.y = (f16)hi;
    return cv.u;
}
static __device__ __forceinline__ u16 f16bits(float v) {
    union { f16 h; u16 u; } cv; cv.h = (f16)v; return cv.u;
}
static __device__ __forceinline__ float fexp(float x) {
    return __builtin_amdgcn_exp2f(x * 1.44269504088896341f);
}
static __device__ __forceinline__ float frcp(float x) {
    return __builtin_amdgcn_rcpf(x);
}
static __device__ __forceinline__ float sigf(float x) {
    return frcp(1.f + fexp(-x));
}
static __device__ __forceinline__ float swz8(float x) {
    // lane <-> lane^8 exchange (BitMode xor-8: offset 0x201F)
    union { float f; int i; } c; c.f = x;
    c.i = __builtin_amdgcn_ds_swizzle(c.i, 0x201F);
    return c.f;
}
static __device__ __forceinline__ float sel4(f32x4 v, int q) {
    // q in 0..3, compile-time indices in each arm (rule #20: no dyn index)
    return (q & 2) ? ((q & 1) ? v[3] : v[2]) : ((q & 1) ? v[1] : v[0]);
}

__global__ __attribute__((amdgpu_flat_work_group_size(512, 512),
                          amdgpu_waves_per_eu(2, 2)))
void bilstm_mfma_ch2_kernel(const int* __restrict__ idx,
                            const float* __restrict__ masks,
                            const float* __restrict__ emb,
                            const float* __restrict__ Wih_f, const float* __restrict__ Whh_f,
                            const float* __restrict__ bih_f, const float* __restrict__ bhh_f,
                            const float* __restrict__ Wih_b, const float* __restrict__ Whh_b,
                            const float* __restrict__ bih_b, const float* __restrict__ bhh_b,
                            float* __restrict__ out)
{
    // Hbuf[buf][kt][c4k][col][j]: value = H[k = kt*32 + c4k*8 + j][col] fp16,
    // col parity = chain (8 copies per chain).
    __shared__ __align__(16) unsigned char Hbuf[2][6 * 1024];  // 12 KB
    __shared__ u16 idx16[CH * TT];                             // 2 KB
    __shared__ u32 mbits[TT];                                  // 2 KB

    const int tid  = threadIdx.x;
    const int lane = tid & 63;
    const int wv   = tid >> 6;        // wave 0..7
    const int l15  = lane & 15;       // acc col
    const int c4   = lane >> 4;       // 0..3 (acc row group)
    const int d    = blockIdx.x & 1;  // 0 fwd, 1 bwd
    const int g    = blockIdx.x >> 1; // 0..127
    const int b0   = g * CH;
    const int rev  = d;

    const int chain = l15 & 1;
    const int cp    = l15 >> 1;       // 0..7 copy index
    const int flag  = cp >> 2;        // 0 = state-owner role, 1 = helper role
    const int q     = cp & 3;         // acc row within c4 group

    const float* Wih = d ? Wih_b : Wih_f;
    const float* Whh = d ? Whh_b : Whh_f;
    const float* bih = d ? bih_b : bih_f;
    const float* bhh = d ? bhh_b : bhh_f;

    // ---- init: idx (u16), mask bitmasks, zero H buffers
    for (int i = tid; i < CH * TT; i += 512) {
        const int m = i >> 9, t = i & 511;
        idx16[i] = (u16)idx[(b0 + m) * TT + t];
    }
    if (tid < TT) {
        u32 mb = 0;
        for (int m = 0; m < CH; ++m)
            mb |= (masks[(b0 + m) * TT + tid] != 0.f ? 1u : 0u) << m;
        mbits[tid] = mb;
    }
    for (int i = tid; i < 2 * 6 * 1024 / 4; i += 512)
        ((u32*)Hbuf)[i] = 0u;

    // ---- W fragments (A-operand) in VGPRs: w[kt][gt], gt = i/f/g/o.
    // Lane provides A[row = gate][k]: gate n = (wv + gt*8)*16 + l15,
    // k = kt*32 + c4*8 + j, j = 0..7.  (identical to R9-R11, proven)
    f16x8 w[6][4];
#pragma unroll
    for (int gt = 0; gt < 4; ++gt) {
        const int n = (wv + gt * 8) * 16 + l15;
        // kt = 0: k = c4*8 + j (< 32 < 50) -> Wih (float2 loads: 8B aligned)
#pragma unroll
        for (int jj = 0; jj < 4; ++jj) {
            const float2 e = *(const float2*)(Wih + n * 50 + c4 * 8 + jj * 2);
            w[0][gt][2 * jj]     = (f16)e.x;
            w[0][gt][2 * jj + 1] = (f16)e.y;
        }
        // kt = 1: k = 32 + c4*8 + j, real iff k < 50
#pragma unroll
        for (int j = 0; j < 8; ++j) {
            const int k = 32 + c4 * 8 + j;
            float v = 0.f;
            if (k < 50) v = Wih[n * 50 + k];
            w[1][gt][j] = (f16)v;
        }
        // kt = 2..5: k >= 64 -> Whh[n][k-64] (16B aligned float4 x2)
#pragma unroll
        for (int kt = 2; kt < 6; ++kt) {
            const int kh = (kt - 2) * 32 + c4 * 8;
            const float4 e0 = *(const float4*)(Whh + n * 128 + kh);
            const float4 e1 = *(const float4*)(Whh + n * 128 + kh + 4);
            w[kt][gt][0] = (f16)e0.x; w[kt][gt][1] = (f16)e0.y;
            w[kt][gt][2] = (f16)e0.z; w[kt][gt][3] = (f16)e0.w;
            w[kt][gt][4] = (f16)e1.x; w[kt][gt][5] = (f16)e1.y;
            w[kt][gt][6] = (f16)e1.z; w[kt][gt][7] = (f16)e1.w;
        }
    }

    // ---- per-lane biases for its single dim hd (post-MFMA add)
    const int hd  = wv * 16 + c4 * 4 + q;
    const float b_i = bih[hd]       + bhh[hd];
    const float b_f = bih[128 + hd] + bhh[128 + hd];
    const float b_g = bih[256 + hd] + bhh[256 + hd];
    const float b_o = bih[384 + hd] + bhh[384 + hd];

    __syncthreads();   // idx16/mbits/Hbuf-zero visible before x store

    // ---- x for step 0: threads 0..399, col pm = 0..15 (chain pm&1, 8 copies)
    if (tid < 400) {
        const int pm = tid / 25, ps = tid % 25;
        const int t0  = rev ? (TT - 1) : 0;
        const int row = idx16[(pm & 1) * TT + t0];
        const float2 e = *(const float2*)(emb + row * 50 + ps * 2);
        const int k0 = 2 * ps;
        const int kt = k0 >> 5, c4k = (k0 >> 3) & 3, j = k0 & 7;
        *(u32*)(&Hbuf[0][(kt << 10) + ((c4k * 16 + pm) << 4) + (j << 1)]) =
            packh2(e.x, e.y);
    }
    __syncthreads();

    float cst0 = 0.f, rm0 = -3e38f;

    // h-writeback: lane writes 4 of the 8 copies of (chain, dim hd).
    // k = 64+hd; copies at col = chain + 2*cp' -> +32B apart; this lane's
    // half starts at flag*4 copies -> +flag*128.
    const int k0h    = 64 + hd;
    const int wb_kt  = k0h >> 5;
    const int wb_c4k = (k0h >> 3) & 3;
    const int wb_j   = k0h & 7;
    const int wb_off = (wb_kt << 10) + ((wb_c4k * 16 + chain) << 4) + (wb_j << 1)
                     + flag * 128;

    for (int s = 0; s < TT; ++s) {
        const int cur = s & 1;
        const int t   = rev ? (TT - 1 - s) : s;

        // prefetch next step's x row-pair (hidden under MFMA)
        float2 e;
        int pk0 = 0;
        const bool pf = (tid < 400) && (s + 1 < TT);
        const int pm = tid / 25, ps = tid % 25;
        if (pf) {
            const int t1  = rev ? (TT - 2 - s) : (s + 1);
            const int row = idx16[(pm & 1) * TT + t1];
            e = *(const float2*)(emb + row * 50 + ps * 2);
            pk0 = 2 * ps;
        }

        // ---- MFMA: 4 gate tiles x 6 K-steps; B-frag = contiguous 16B/lane
        const unsigned char* hb = &Hbuf[cur][0];
        const f32x4 z = {0.f, 0.f, 0.f, 0.f};
        f32x4 ai = z, af = z, ag = z, ao = z;
#pragma unroll
        for (int kt = 0; kt < 6; ++kt) {
            const f16x8 bf = *(const f16x8*)(hb + (kt << 10) + (lane << 4));
            ai = __builtin_amdgcn_mfma_f32_16x16x32_f16(w[kt][0], bf, ai, 0, 0, 0);
            af = __builtin_amdgcn_mfma_f32_16x16x32_f16(w[kt][1], bf, af, 0, 0, 0);
            ag = __builtin_amdgcn_mfma_f32_16x16x32_f16(w[kt][2], bf, ag, 0, 0, 0);
            ao = __builtin_amdgcn_mfma_f32_16x16x32_f16(w[kt][3], bf, ao, 0, 0, 0);
        }

        // ---- q-row select + bias (cols 8x duplicated -> pair holds same)
        const float iv = sel4(ai, q) + b_i;
        const float fv = sel4(af, q) + b_f;
        const float gv = sel4(ag, q) + b_g;
        const float ov = sel4(ao, q) + b_o;

        // ---- SIMT role-split activation (no divergence):
        // role A (flag=0): su=sig(f), sv=sig(i);  role B: su=sig(2g), sv=sig(o)
        const bool fB = (flag != 0);
        const float u = fB ? (gv + gv) : fv;
        const float v = fB ? ov : iv;
        const float su = sigf(u);
        const float sv = sigf(v);
        const float tg_send = 2.f * su - 1.f;     // B: tanh(g); A: junk
        const float tgx = swz8(tg_send);          // A receives tanh(g)
        const float svx = swz8(sv);               // A receives sig(o)
        // A: cc = sig(f)*c + sig(i)*tanh(g); B: finite junk (cst0 junk-chain)
        const float cc = su * cst0 + sv * tgx;
        cst0 = cc;
        const float ccx = swz8(cc);               // B receives A's cc
        const float cc_use = fB ? ccx : cc;
        const float th = 2.f * sigf(cc_use + cc_use) - 1.f;   // tanh(c)
        const float so_use = fB ? sv : svx;       // sig(o) in both roles
        const float hh = so_use * th;

        const float pen = ((mbits[t] >> chain) & 1u) ? 0.f : 1e8f;
        rm0 = fmaxf(rm0, hh - pen);

        // ---- writes: this lane's 4 column copies (+0,+32,+64,+96)
        unsigned char* nb = &Hbuf[cur ^ 1][0];
        {
            const u16 pk = f16bits(hh);
            *(u16*)(nb + wb_off)      = pk;
            *(u16*)(nb + wb_off + 32) = pk;
            *(u16*)(nb + wb_off + 64) = pk;
            *(u16*)(nb + wb_off + 96) = pk;
        }
        if (pf) {
            const int kt = pk0 >> 5, c4k = (pk0 >> 3) & 3, j = pk0 & 7;
            *(u32*)(nb + (kt << 10) + ((c4k * 16 + pm) << 4) + (j << 1)) =
                packh2(e.x, e.y);
        }
        __syncthreads();
    }

    // ---- output: role-A lanes only (one lane per (chain, dim) task)
    if (!flag) {
        out[(b0 + chain) * 256 + d * 128 + hd] = rm0;
    }
}

extern "C" void kernel_launch(void* const* d_in, const int* in_sizes, int n_in,
                              void* d_out, int out_size, void* d_ws, size_t ws_size,
                              hipStream_t stream) {
    const int*   idx   = (const int*)d_in[0];
    const float* masks = (const float*)d_in[1];
    const float* emb   = (const float*)d_in[2];
    const float* Wih_f = (const float*)d_in[3];
    const float* Whh_f = (const float*)d_in[4];
    const float* bih_f = (const float*)d_in[5];
    const float* bhh_f = (const float*)d_in[6];
    const float* Wih_b = (const float*)d_in[7];
    const float* Whh_b = (const float*)d_in[8];
    const float* bih_b = (const float*)d_in[9];
    const float* bhh_b = (const float*)d_in[10];
    float* out = (float*)d_out;

    bilstm_mfma_ch2_kernel<<<dim3(256), dim3(512), 0, stream>>>(
        idx, masks, emb,
        Wih_f, Whh_f, bih_f, bhh_f,
        Wih_b, Whh_b, bih_b, bhh_b,
        out);
}

// Round 13
// 397.786 us; speedup vs baseline: 1.0674x; 1.0674x over previous
//
#include <hip/hip_runtime.h>
#include <hip/hip_fp16.h>

// Bidirectional char-LSTM + masked max-pool via MFMA, operand-swapped,
// CH=2 with 8x-duplicated B-columns + SIMT role-split activation, DPP xchg.
// 256 blocks = 2 dirs x 128 chain-pairs -> ALL 256 CUs.
// Each (chain,dim) task is owned by a LANE PAIR (l15, l15^8) holding
// identical gate values (8x col duplication). Role A (flag=0): sig(f),sig(i);
// role B: sig(2g),sig(o) -- same instruction stream, cndmask-selected inputs
// (tanh(x)=2*sig(2x)-1). Wave-level trans issue: 6 ops (R11: 10).
// R12 lesson: ds_swizzle exchanges are DS ops with ~60cyc lgkm latency,
// serially chained -> ate the gain. R13: lane^8 == DPP row_ror:8 (VALU,
// ~2cyc). Bias restored to MFMA acc-init (off the critical path).
// Per step: D'[512 gates][16 cols(2 chains x8)] = W[512][192] x H[192][16]
// via mfma_f32_16x16x32_f16; W static in VGPRs (24 f16x8/wave); H in LDS,
// fragment-ordered (lane l reads bytes [l*16,l*16+16) -> conflict-free).
// h-writeback: 8 copies split 4+4 across the pair. One barrier per step.

#define TT 512
#define CH 2

typedef _Float16 f16;
typedef _Float16 f16x8 __attribute__((ext_vector_type(8)));
typedef float f32x4 __attribute__((ext_vector_type(4)));
typedef unsigned int u32;
typedef unsigned short u16;

static __device__ __forceinline__ u32 packh2(float lo, float hi) {
    union { struct { f16 x, y; } h; u32 u; } cv;
    cv.h.x = (f16)lo; cv.h.y = (f16)hi;
    return cv.u;
}
static __device__ __forceinline__ u16 f16bits(float v) {
    union { f16 h; u16 u; } cv; cv.h = (f16)v; return cv.u;
}
static __device__ __forceinline__ float fexp(float x) {
    return __builtin_amdgcn_exp2f(x * 1.44269504088896341f);
}
static __device__ __forceinline__ float frcp(float x) {
    return __builtin_amdgcn_rcpf(x);
}
static __device__ __forceinline__ float sigf(float x) {
    return frcp(1.f + fexp(-x));
}
static __device__ __forceinline__ float xor8(float x) {
    // lane <-> lane^8: DPP row_ror:8 (rotate by 8 within rows of 16 == xor 8)
    union { float f; int i; } c; c.f = x;
#if __has_builtin(__builtin_amdgcn_mov_dpp)
    c.i = __builtin_amdgcn_mov_dpp(c.i, 0x128, 0xF, 0xF, 0);
#elif __has_builtin(__builtin_amdgcn_update_dpp)
    c.i = __builtin_amdgcn_update_dpp(c.i, c.i, 0x128, 0xF, 0xF, 0);
#else
    c.i = __builtin_amdgcn_ds_swizzle(c.i, 0x201F);
#endif
    return c.f;
}
static __device__ __forceinline__ float sel4(f32x4 v, int q) {
    // q in 0..3, compile-time indices in each arm (rule #20: no dyn index)
    return (q & 2) ? ((q & 1) ? v[3] : v[2]) : ((q & 1) ? v[1] : v[0]);
}

__global__ __attribute__((amdgpu_flat_work_group_size(512, 512),
                          amdgpu_waves_per_eu(2, 2)))
void bilstm_mfma_dpp_kernel(const int* __restrict__ idx,
                            const float* __restrict__ masks,
                            const float* __restrict__ emb,
                            const float* __restrict__ Wih_f, const float* __restrict__ Whh_f,
                            const float* __restrict__ bih_f, const float* __restrict__ bhh_f,
                            const float* __restrict__ Wih_b, const float* __restrict__ Whh_b,
                            const float* __restrict__ bih_b, const float* __restrict__ bhh_b,
                            float* __restrict__ out)
{
    // Hbuf[buf][kt][c4k][col][j]: value = H[k = kt*32 + c4k*8 + j][col] fp16,
    // col parity = chain (8 copies per chain).
    __shared__ __align__(16) unsigned char Hbuf[2][6 * 1024];  // 12 KB
    __shared__ u16 idx16[CH * TT];                             // 2 KB
    __shared__ u32 mbits[TT];                                  // 2 KB

    const int tid  = threadIdx.x;
    const int lane = tid & 63;
    const int wv   = tid >> 6;        // wave 0..7
    const int l15  = lane & 15;       // acc col
    const int c4   = lane >> 4;       // 0..3 (acc row group)
    const int d    = blockIdx.x & 1;  // 0 fwd, 1 bwd
    const int g    = blockIdx.x >> 1; // 0..127
    const int b0   = g * CH;
    const int rev  = d;

    const int chain = l15 & 1;
    const int cp    = l15 >> 1;       // 0..7 copy index
    const int flag  = cp >> 2;        // 0 = state-owner role, 1 = helper role
    const int q     = cp & 3;         // acc row within c4 group

    const float* Wih = d ? Wih_b : Wih_f;
    const float* Whh = d ? Whh_b : Whh_f;
    const float* bih = d ? bih_b : bih_f;
    const float* bhh = d ? bhh_b : bhh_f;

    // ---- init: idx (u16), mask bitmasks, zero H buffers
    for (int i = tid; i < CH * TT; i += 512) {
        const int m = i >> 9, t = i & 511;
        idx16[i] = (u16)idx[(b0 + m) * TT + t];
    }
    if (tid < TT) {
        u32 mb = 0;
        for (int m = 0; m < CH; ++m)
            mb |= (masks[(b0 + m) * TT + tid] != 0.f ? 1u : 0u) << m;
        mbits[tid] = mb;
    }
    for (int i = tid; i < 2 * 6 * 1024 / 4; i += 512)
        ((u32*)Hbuf)[i] = 0u;

    // ---- W fragments (A-operand) in VGPRs: w[kt][gt], gt = i/f/g/o.
    // Lane provides A[row = gate][k]: gate n = (wv + gt*8)*16 + l15,
    // k = kt*32 + c4*8 + j, j = 0..7.  (identical to R9-R12, proven)
    f16x8 w[6][4];
    f32x4 bias4[4];
#pragma unroll
    for (int gt = 0; gt < 4; ++gt) {
        const int n = (wv + gt * 8) * 16 + l15;
        {   // bias for acc rows: gates (wv+gt*8)*16 + c4*4 + q', q'=0..3
            const int nb_ = (wv + gt * 8) * 16 + c4 * 4;
            const float4 bi = *(const float4*)(bih + nb_);
            const float4 bh = *(const float4*)(bhh + nb_);
            bias4[gt][0] = bi.x + bh.x; bias4[gt][1] = bi.y + bh.y;
            bias4[gt][2] = bi.z + bh.z; bias4[gt][3] = bi.w + bh.w;
        }
        // kt = 0: k = c4*8 + j (< 32 < 50) -> Wih (float2 loads: 8B aligned)
#pragma unroll
        for (int jj = 0; jj < 4; ++jj) {
            const float2 e = *(const float2*)(Wih + n * 50 + c4 * 8 + jj * 2);
            w[0][gt][2 * jj]     = (f16)e.x;
            w[0][gt][2 * jj + 1] = (f16)e.y;
        }
        // kt = 1: k = 32 + c4*8 + j, real iff k < 50
#pragma unroll
        for (int j = 0; j < 8; ++j) {
            const int k = 32 + c4 * 8 + j;
            float v = 0.f;
            if (k < 50) v = Wih[n * 50 + k];
            w[1][gt][j] = (f16)v;
        }
        // kt = 2..5: k >= 64 -> Whh[n][k-64] (16B aligned float4 x2)
#pragma unroll
        for (int kt = 2; kt < 6; ++kt) {
            const int kh = (kt - 2) * 32 + c4 * 8;
            const float4 e0 = *(const float4*)(Whh + n * 128 + kh);
            const float4 e1 = *(const float4*)(Whh + n * 128 + kh + 4);
            w[kt][gt][0] = (f16)e0.x; w[kt][gt][1] = (f16)e0.y;
            w[kt][gt][2] = (f16)e0.z; w[kt][gt][3] = (f16)e0.w;
            w[kt][gt][4] = (f16)e1.x; w[kt][gt][5] = (f16)e1.y;
            w[kt][gt][6] = (f16)e1.z; w[kt][gt][7] = (f16)e1.w;
        }
    }

    __syncthreads();   // idx16/mbits/Hbuf-zero visible before x store

    // ---- x for step 0: threads 0..399, col pm = 0..15 (chain pm&1, 8 copies)
    if (tid < 400) {
        const int pm = tid / 25, ps = tid % 25;
        const int t0  = rev ? (TT - 1) : 0;
        const int row = idx16[(pm & 1) * TT + t0];
        const float2 e = *(const float2*)(emb + row * 50 + ps * 2);
        const int k0 = 2 * ps;
        const int kt = k0 >> 5, c4k = (k0 >> 3) & 3, j = k0 & 7;
        *(u32*)(&Hbuf[0][(kt << 10) + ((c4k * 16 + pm) << 4) + (j << 1)]) =
            packh2(e.x, e.y);
    }
    __syncthreads();

    float cst0 = 0.f, rm0 = -3e38f;

    // h-writeback: lane writes 4 of the 8 copies of (chain, dim hd).
    const int hd     = wv * 16 + c4 * 4 + q;
    const int k0h    = 64 + hd;
    const int wb_kt  = k0h >> 5;
    const int wb_c4k = (k0h >> 3) & 3;
    const int wb_j   = k0h & 7;
    const int wb_off = (wb_kt << 10) + ((wb_c4k * 16 + chain) << 4) + (wb_j << 1)
                     + flag * 128;

    for (int s = 0; s < TT; ++s) {
        const int cur = s & 1;
        const int t   = rev ? (TT - 1 - s) : s;

        // prefetch next step's x row-pair (hidden under MFMA)
        float2 e;
        int pk0 = 0;
        const bool pf = (tid < 400) && (s + 1 < TT);
        const int pm = tid / 25, ps = tid % 25;
        if (pf) {
            const int t1  = rev ? (TT - 2 - s) : (s + 1);
            const int row = idx16[(pm & 1) * TT + t1];
            e = *(const float2*)(emb + row * 50 + ps * 2);
            pk0 = 2 * ps;
        }

        // ---- MFMA: 4 gate tiles x 6 K-steps; B-frag = contiguous 16B/lane
        const unsigned char* hb = &Hbuf[cur][0];
        f32x4 ai = bias4[0], af = bias4[1], ag = bias4[2], ao = bias4[3];
#pragma unroll
        for (int kt = 0; kt < 6; ++kt) {
            const f16x8 bf = *(const f16x8*)(hb + (kt << 10) + (lane << 4));
            ai = __builtin_amdgcn_mfma_f32_16x16x32_f16(w[kt][0], bf, ai, 0, 0, 0);
            af = __builtin_amdgcn_mfma_f32_16x16x32_f16(w[kt][1], bf, af, 0, 0, 0);
            ag = __builtin_amdgcn_mfma_f32_16x16x32_f16(w[kt][2], bf, ag, 0, 0, 0);
            ao = __builtin_amdgcn_mfma_f32_16x16x32_f16(w[kt][3], bf, ao, 0, 0, 0);
        }

        // ---- q-row select (cols 8x duplicated -> pair holds same values)
        const float iv = sel4(ai, q);
        const float fv = sel4(af, q);
        const float gv = sel4(ag, q);
        const float ov = sel4(ao, q);

        // ---- SIMT role-split activation, DPP transport (no divergence):
        // role A (flag=0): su=sig(f), sv=sig(i);  role B: su=sig(2g), sv=sig(o)
        const bool fB = (flag != 0);
        const float u = fB ? (gv + gv) : fv;
        const float v = fB ? ov : iv;
        const float su = sigf(u);
        const float sv = sigf(v);
        const float tg_send = 2.f * su - 1.f;     // B: tanh(g); A: junk
        const float tgx = xor8(tg_send);          // A receives tanh(g)
        const float svx = xor8(sv);               // A receives sig(o)
        // A: cc = sig(f)*c + sig(i)*tanh(g); B: finite junk (bounded chain)
        const float cc = su * cst0 + sv * tgx;
        cst0 = cc;
        const float ccx = xor8(cc);               // B receives A's cc
        const float cc_use = fB ? ccx : cc;
        const float th = 2.f * sigf(cc_use + cc_use) - 1.f;   // tanh(c)
        const float so_use = fB ? sv : svx;       // sig(o) in both roles
        const float hh = so_use * th;

        const float pen = ((mbits[t] >> chain) & 1u) ? 0.f : 1e8f;
        rm0 = fmaxf(rm0, hh - pen);

        // ---- writes: this lane's 4 column copies (+0,+32,+64,+96)
        unsigned char* nb = &Hbuf[cur ^ 1][0];
        {
            const u16 pk = f16bits(hh);
            *(u16*)(nb + wb_off)      = pk;
            *(u16*)(nb + wb_off + 32) = pk;
            *(u16*)(nb + wb_off + 64) = pk;
            *(u16*)(nb + wb_off + 96) = pk;
        }
        if (pf) {
            const int kt = pk0 >> 5, c4k = (pk0 >> 3) & 3, j = pk0 & 7;
            *(u32*)(nb + (kt << 10) + ((c4k * 16 + pm) << 4) + (j << 1)) =
                packh2(e.x, e.y);
        }
        __syncthreads();
    }

    // ---- output: role-A lanes only (one lane per (chain, dim) task)
    if (!flag) {
        out[(b0 + chain) * 256 + d * 128 + hd] = rm0;
    }
}

extern "C" void kernel_launch(void* const* d_in, const int* in_sizes, int n_in,
                              void* d_out, int out_size, void* d_ws, size_t ws_size,
                              hipStream_t stream) {
    const int*   idx   = (const int*)d_in[0];
    const float* masks = (const float*)d_in[1];
    const float* emb   = (const float*)d_in[2];
    const float* Wih_f = (const float*)d_in[3];
    const float* Whh_f = (const float*)d_in[4];
    const float* bih_f = (const float*)d_in[5];
    const float* bhh_f = (const float*)d_in[6];
    const float* Wih_b = (const float*)d_in[7];
    const float* Whh_b = (const float*)d_in[8];
    const float* bih_b = (const float*)d_in[9];
    const float* bhh_b = (const float*)d_in[10];
    float* out = (float*)d_out;

    bilstm_mfma_dpp_kernel<<<dim3(256), dim3(512), 0, stream>>>(
        idx, masks, emb,
        Wih_f, Whh_f, bih_f, bhh_f,
        Wih_b, Whh_b, bih_b, bhh_b,
        out);
}